// Round 8
// baseline (114.093 us; speedup 1.0000x reference)
//
#include <hip/hip_runtime.h>

#define HH 768
#define WW 768
#define HP 770
#define WP 770
#define ROWS 16
#define TILES 192   // 4 output cols per thread; 192*4 = 768
#define BANDS 48    // 48*16 = 768
#define NBLK (TILES * BANDS * 32 / 256)   // 1152 blocks
#define CHUNK (NBLK / 8)                  // 144 per XCD

// Register-carried row-walking stencil, 4 cols x 16 rows per thread,
// 1-row software prefetch, lane-shuffle column halos.
// Collapsed algebra (R0 derivation):
//   Au(i,j) = 0.5 * [ -(v2+v4)@P00 + (v2-v3)@P01 + (v4-v1)@P10 + (v1+v3)@P11 ]
// Weight coords (original 770-wide) never clamp; u clamps rows/right cols at 767.
// Column halo (cols j0+4, j0+5) comes from lane+1 via shfl_down: every wave is
// 64 consecutive tiles of one band (192 % 64 == 0), so lane L+1 owns tile+1.
// Lane 63 fixes up with predicated scalar loads; tile 191 clamps in-register.

typedef float f4 __attribute__((ext_vector_type(4)));

__device__ inline f4 ld4u(const float* p) {
    f4 v;
    __builtin_memcpy(&v, p, sizeof(f4));   // 4B-aligned dwordx4
    return v;
}

__global__ __launch_bounds__(256) void diffusion_kernel(
    const float* __restrict__ u,
    const float* __restrict__ a,
    const float* __restrict__ b,
    const float* __restrict__ c,
    const float* __restrict__ alpha_p,
    const float* __restrict__ tau_p,
    float* __restrict__ out)
{
    // XCD-bijective swizzle: 1152 = 8 * 144
    const int bid  = (blockIdx.x & 7) * CHUNK + (blockIdx.x >> 3);
    const int gtid = bid * 256 + threadIdx.x;
    const int tile = gtid % TILES;
    const int band = (gtid / TILES) % BANDS;
    const int bc   = gtid / (TILES * BANDS);
    const int lane = threadIdx.x & 63;
    const int j0 = tile * 4;
    const int i0 = band * ROWS;
    const bool edge = (lane == 63);
    const bool last_tile = (tile == TILES - 1);

    const float alpha = *alpha_p;
    const float tau_h = 0.5f * (*tau_p);
    const float c1 = (1.0f - alpha) * 0.5f;
    const float c2 = alpha * 0.5f;
    const float g  = 1.0f - 2.0f * alpha;

    const float* __restrict__ ub = u + (size_t)bc * (HH * WW);
    const float* __restrict__ ab = a + (size_t)bc * (HP * WP);
    const float* __restrict__ bb = b + (size_t)bc * (HP * WP);
    const float* __restrict__ cb = c + (size_t)bc * (HP * WP);
    float* __restrict__ outb = out + (size_t)bc * (HH * WW);

    // carried: u rows i,i+1,i+2 (6 cols); weight rows i+1,i+2 (5 cols)
    float u0[6], u1[6], u2[6];
    float a1[5], a2[5], b1[5], b2[5], cc1[5], cc2[5];

    // load one u row: own f4 + halo via shfl from lane+1, lane-63 fixup
    auto load_u = [&](int row, float* dst) {
        const float* pr = ub + (size_t)row * WW + j0;
        f4 t0 = *(const f4*)pr;
        dst[0] = t0.x; dst[1] = t0.y; dst[2] = t0.z; dst[3] = t0.w;
        dst[4] = __shfl_down(t0.x, 1);
        dst[5] = __shfl_down(t0.y, 1);
        if (edge) {
            if (last_tile) { dst[4] = t0.w; dst[5] = t0.w; }   // cols 768,769 -> 767
            else           { dst[4] = pr[4]; dst[5] = pr[5]; }
        }
    };
    // load one weight row: own f4 (cols j0+1..j0+4) + halo col j0+5 via shfl
    auto load_w = [&](const float* base, int row, float* dst) {
        const float* pr = base + (size_t)row * WP + (j0 + 1);
        f4 t = ld4u(pr);
        dst[0] = t.x; dst[1] = t.y; dst[2] = t.z; dst[3] = t.w;
        dst[4] = __shfl_down(t.x, 1);
        if (edge) dst[4] = pr[4];    // col j0+5 <= 769: always in bounds
    };

    // prologue for first output row i0
    load_u(i0,     u0);
    load_u(i0 + 1, u1);
    load_u(i0 + 2, u2);
    load_w(ab, i0 + 1, a1);  load_w(ab, i0 + 2, a2);
    load_w(bb, i0 + 1, b1);  load_w(bb, i0 + 2, b2);
    load_w(cb, i0 + 1, cc1); load_w(cb, i0 + 2, cc2);

    auto wts = [&](float Av, float Bv, float Cv,
                   float& w1a, float& w2a, float& w1b, float& w2b,
                   float& w1c, float& w2c) {
        w1a = Av * c1; w2a = Av * c2;
        const float gb = g * fabsf(Bv);
        w1b = (Bv - gb) * 0.25f; w2b = (Bv + gb) * 0.25f;
        w1c = Cv * c1; w2c = Cv * c2;
    };

#pragma unroll
    for (int r = 0; r < ROWS; ++r) {
        const int ri = i0 + r;

        // ---- prefetch row ri+3 (u row-clamped; weight rows <= 769 in bounds) ----
        float pu[6], pa[5], pb[5], pc[5];
        if (r < ROWS - 1) {
            load_u(min(ri + 3, HH - 1), pu);
            load_w(ab, ri + 3, pa);
            load_w(bb, ri + 3, pb);
            load_w(cb, ri + 3, pc);
        }

        // ---- compute output row ri (4 cols) ----
        float res[4];
#pragma unroll
        for (int p = 0; p < 4; ++p) {
            float acc = 0.0f;
            float w1a, w2a, w1b, w2b, w1c, w2c;
            float ux1, ux2, uy1, uy2;

            // P00: s = -(v2+v4)
            wts(a1[p], b1[p], cc1[p], w1a, w2a, w1b, w2b, w1c, w2c);
            ux1 = u0[p+1] - u0[p];   ux2 = u1[p+1] - u1[p];
            uy1 = u1[p]   - u0[p];   uy2 = u1[p+1] - u0[p+1];
            acc -= (w2a + w2b) * ux1 + (w1a + w1b) * ux2
                 + (w2b + w2c) * uy1 + (w1b + w1c) * uy2;

            // P01: s = v2 - v3
            wts(a1[p+1], b1[p+1], cc1[p+1], w1a, w2a, w1b, w2b, w1c, w2c);
            ux1 = u0[p+2] - u0[p+1]; ux2 = u1[p+2] - u1[p+1];
            uy1 = u1[p+1] - u0[p+1]; uy2 = u1[p+2] - u0[p+2];
            acc += (w2a - w1b) * ux1 + (w1a - w2b) * ux2
                 + (w2b - w1c) * uy1 + (w1b - w2c) * uy2;

            // P10: s = v4 - v1
            wts(a2[p], b2[p], cc2[p], w1a, w2a, w1b, w2b, w1c, w2c);
            ux1 = u1[p+1] - u1[p];   ux2 = u2[p+1] - u2[p];
            uy1 = u2[p]   - u1[p];   uy2 = u2[p+1] - u1[p+1];
            acc += (w2b - w1a) * ux1 + (w1b - w2a) * ux2
                 + (w2c - w1b) * uy1 + (w1c - w2b) * uy2;

            // P11: s = v1 + v3
            wts(a2[p+1], b2[p+1], cc2[p+1], w1a, w2a, w1b, w2b, w1c, w2c);
            ux1 = u1[p+2] - u1[p+1]; ux2 = u2[p+2] - u2[p+1];
            uy1 = u2[p+1] - u1[p+1]; uy2 = u2[p+2] - u1[p+2];
            acc += (w1a + w1b) * ux1 + (w2a + w2b) * ux2
                 + (w1b + w1c) * uy1 + (w2b + w2c) * uy2;

            res[p] = u0[p] + tau_h * acc;
        }

        f4 o;
        o.x = res[0]; o.y = res[1]; o.z = res[2]; o.w = res[3];
        __builtin_nontemporal_store(o, (f4*)(outb + (size_t)ri * WW + j0));

        // ---- rotate carried registers (renamed away under full unroll) ----
        if (r < ROWS - 1) {
#pragma unroll
            for (int q = 0; q < 6; ++q) { u0[q] = u1[q]; u1[q] = u2[q]; u2[q] = pu[q]; }
#pragma unroll
            for (int q = 0; q < 5; ++q) {
                a1[q] = a2[q];  a2[q] = pa[q];
                b1[q] = b2[q];  b2[q] = pb[q];
                cc1[q] = cc2[q]; cc2[q] = pc[q];
            }
        }
    }
}

extern "C" void kernel_launch(void* const* d_in, const int* in_sizes, int n_in,
                              void* d_out, int out_size, void* d_ws, size_t ws_size,
                              hipStream_t stream) {
    const float* u     = (const float*)d_in[0];
    const float* a     = (const float*)d_in[1];
    const float* b     = (const float*)d_in[2];
    const float* c     = (const float*)d_in[3];
    const float* alpha = (const float*)d_in[8];
    const float* tau   = (const float*)d_in[9];
    float* out = (float*)d_out;

    dim3 block(256, 1, 1);
    dim3 grid(NBLK, 1, 1);
    diffusion_kernel<<<grid, block, 0, stream>>>(u, a, b, c, alpha, tau, out);
}

// Round 9
// 71.325 us; speedup vs baseline: 1.5996x; 1.5996x over previous
//
#include <hip/hip_runtime.h>

#define HH 768
#define WW 768
#define HP 770
#define WP 770
#define ROWS 8
#define TILES 192   // 4 output cols per thread; 192*4 = 768
#define BANDS 96    // 96*8 = 768
#define NBLK (TILES * BANDS * 32 / 256)   // 2304 blocks
#define CHUNK (NBLK / 8)                  // 288 per XCD

// Register-carried row-walking stencil, 4 cols x 8 rows per thread,
// DEPTH-2 software prefetch (two pending row-sets in flight).
// Collapsed algebra (R0 derivation):
//   Au(i,j) = 0.5 * [ -(v2+v4)@P00 + (v2-v3)@P01 + (v4-v1)@P10 + (v1+v3)@P11 ]
// Weight coords (original 770-wide) never clamp; u clamps rows/right cols at 767.

typedef float f4 __attribute__((ext_vector_type(4)));

__device__ inline f4 ld4u(const float* p) {
    f4 v;
    __builtin_memcpy(&v, p, sizeof(f4));   // 4B-aligned dwordx4
    return v;
}

__global__ __launch_bounds__(256) void diffusion_kernel(
    const float* __restrict__ u,
    const float* __restrict__ a,
    const float* __restrict__ b,
    const float* __restrict__ c,
    const float* __restrict__ alpha_p,
    const float* __restrict__ tau_p,
    float* __restrict__ out)
{
    // XCD-bijective swizzle: 2304 = 8 * 288
    const int bid  = (blockIdx.x & 7) * CHUNK + (blockIdx.x >> 3);
    const int gtid = bid * 256 + threadIdx.x;
    const int tile = gtid % TILES;
    const int band = (gtid / TILES) % BANDS;
    const int bc   = gtid / (TILES * BANDS);
    const int j0 = tile * 4;
    const int i0 = band * ROWS;
    const bool interior = (j0 + 4) < WW;    // false only for tile 191 (j0=764)

    const float alpha = *alpha_p;
    const float tau_h = 0.5f * (*tau_p);
    const float c1 = (1.0f - alpha) * 0.5f;
    const float c2 = alpha * 0.5f;
    const float g  = 1.0f - 2.0f * alpha;

    const float* __restrict__ ub = u + (size_t)bc * (HH * WW);
    const float* __restrict__ ab = a + (size_t)bc * (HP * WP);
    const float* __restrict__ bb = b + (size_t)bc * (HP * WP);
    const float* __restrict__ cb = c + (size_t)bc * (HP * WP);
    float* __restrict__ outb = out + (size_t)bc * (HH * WW);

    // carried: u rows i,i+1,i+2 (6 cols); weight rows i+1,i+2 (5 cols)
    float u0[6], u1[6], u2[6];
    float a1[5], a2[5], b1[5], b2[5], cc1[5], cc2[5];
    // pending row-sets (depth-2 pipeline)
    float Au_[6], Aa[5], Ab[5], Ac[5];
    float Bu_[6], Ba[5], Bb[5], Bc[5];

    auto load_u = [&](int row, float* dst) {
        const float* pr = ub + (size_t)row * WW + j0;
        f4 t0 = *(const f4*)pr;
        f4 t1 = *(const f4*)(pr + (interior ? 4 : 0));
        dst[0] = t0.x; dst[1] = t0.y; dst[2] = t0.z; dst[3] = t0.w;
        dst[4] = interior ? t1.x : t0.w;
        dst[5] = interior ? t1.y : t0.w;
    };
    auto load_w = [&](const float* base, int row, float* dst) {
        const float* pr = base + (size_t)row * WP + (j0 + 1);
        f4 t = ld4u(pr);
        dst[0] = t.x; dst[1] = t.y; dst[2] = t.z; dst[3] = t.w;
        dst[4] = pr[4];
    };
    auto load_set = [&](int row, float* du, float* da, float* db, float* dc) {
        load_u(min(row, HH - 1), du);      // u row-clamped
        load_w(ab, row, da);               // weight rows <= i0+9 <= 769: in bounds
        load_w(bb, row, db);
        load_w(cb, row, dc);
    };

    // prologue: carried rows for r=0, then two pending sets
    load_u(i0,     u0);
    load_u(i0 + 1, u1);
    load_u(i0 + 2, u2);
    load_w(ab, i0 + 1, a1);  load_w(ab, i0 + 2, a2);
    load_w(bb, i0 + 1, b1);  load_w(bb, i0 + 2, b2);
    load_w(cb, i0 + 1, cc1); load_w(cb, i0 + 2, cc2);
    load_set(i0 + 3, Au_, Aa, Ab, Ac);
    load_set(i0 + 4, Bu_, Ba, Bb, Bc);

    auto wts = [&](float Av, float Bv, float Cv,
                   float& w1a, float& w2a, float& w1b, float& w2b,
                   float& w1c, float& w2c) {
        w1a = Av * c1; w2a = Av * c2;
        const float gb = g * fabsf(Bv);
        w1b = (Bv - gb) * 0.25f; w2b = (Bv + gb) * 0.25f;
        w1c = Cv * c1; w2c = Cv * c2;
    };

#pragma unroll
    for (int r = 0; r < ROWS; ++r) {
        const int ri = i0 + r;

        // ---- refill B (free since last rotate moved B->A); rows i0+5..i0+9 ----
        if (r >= 1 && r <= ROWS - 3) {
            load_set(ri + 4, Bu_, Ba, Bb, Bc);
        }

        // ---- compute output row ri (4 cols) from carried registers ----
        float res[4];
#pragma unroll
        for (int p = 0; p < 4; ++p) {
            float acc = 0.0f;
            float w1a, w2a, w1b, w2b, w1c, w2c;
            float ux1, ux2, uy1, uy2;

            // P00: s = -(v2+v4)
            wts(a1[p], b1[p], cc1[p], w1a, w2a, w1b, w2b, w1c, w2c);
            ux1 = u0[p+1] - u0[p];   ux2 = u1[p+1] - u1[p];
            uy1 = u1[p]   - u0[p];   uy2 = u1[p+1] - u0[p+1];
            acc -= (w2a + w2b) * ux1 + (w1a + w1b) * ux2
                 + (w2b + w2c) * uy1 + (w1b + w1c) * uy2;

            // P01: s = v2 - v3
            wts(a1[p+1], b1[p+1], cc1[p+1], w1a, w2a, w1b, w2b, w1c, w2c);
            ux1 = u0[p+2] - u0[p+1]; ux2 = u1[p+2] - u1[p+1];
            uy1 = u1[p+1] - u0[p+1]; uy2 = u1[p+2] - u0[p+2];
            acc += (w2a - w1b) * ux1 + (w1a - w2b) * ux2
                 + (w2b - w1c) * uy1 + (w1b - w2c) * uy2;

            // P10: s = v4 - v1
            wts(a2[p], b2[p], cc2[p], w1a, w2a, w1b, w2b, w1c, w2c);
            ux1 = u1[p+1] - u1[p];   ux2 = u2[p+1] - u2[p];
            uy1 = u2[p]   - u1[p];   uy2 = u2[p+1] - u1[p+1];
            acc += (w2b - w1a) * ux1 + (w1b - w2a) * ux2
                 + (w2c - w1b) * uy1 + (w1c - w2b) * uy2;

            // P11: s = v1 + v3
            wts(a2[p+1], b2[p+1], cc2[p+1], w1a, w2a, w1b, w2b, w1c, w2c);
            ux1 = u1[p+2] - u1[p+1]; ux2 = u2[p+2] - u2[p+1];
            uy1 = u2[p+1] - u1[p+1]; uy2 = u2[p+2] - u1[p+2];
            acc += (w1a + w1b) * ux1 + (w2a + w2b) * ux2
                 + (w1b + w1c) * uy1 + (w2b + w2c) * uy2;

            res[p] = u0[p] + tau_h * acc;
        }

        f4 o;
        o.x = res[0]; o.y = res[1]; o.z = res[2]; o.w = res[3];
        __builtin_nontemporal_store(o, (f4*)(outb + (size_t)ri * WW + j0));

        // ---- rotate: consume pending A; promote B->A (renamed under unroll) ----
        if (r < ROWS - 1) {
#pragma unroll
            for (int q = 0; q < 6; ++q) {
                u0[q] = u1[q]; u1[q] = u2[q]; u2[q] = Au_[q]; Au_[q] = Bu_[q];
            }
#pragma unroll
            for (int q = 0; q < 5; ++q) {
                a1[q] = a2[q];   a2[q] = Aa[q];  Aa[q] = Ba[q];
                b1[q] = b2[q];   b2[q] = Ab[q];  Ab[q] = Bb[q];
                cc1[q] = cc2[q]; cc2[q] = Ac[q]; Ac[q] = Bc[q];
            }
        }
    }
}

extern "C" void kernel_launch(void* const* d_in, const int* in_sizes, int n_in,
                              void* d_out, int out_size, void* d_ws, size_t ws_size,
                              hipStream_t stream) {
    const float* u     = (const float*)d_in[0];
    const float* a     = (const float*)d_in[1];
    const float* b     = (const float*)d_in[2];
    const float* c     = (const float*)d_in[3];
    const float* alpha = (const float*)d_in[8];
    const float* tau   = (const float*)d_in[9];
    float* out = (float*)d_out;

    dim3 block(256, 1, 1);
    dim3 grid(NBLK, 1, 1);
    diffusion_kernel<<<grid, block, 0, stream>>>(u, a, b, c, alpha, tau, out);
}

// Round 10
// 67.896 us; speedup vs baseline: 1.6804x; 1.0505x over previous
//
#include <hip/hip_runtime.h>

#define HH 768
#define WW 768
#define HP 770
#define WP 770
#define ROWS 8
#define TILES 192   // 4 output cols per thread; 192*4 = 768
#define BANDS 96    // 96*8 = 768
#define NBLK (TILES * BANDS * 32 / 256)   // 2304 blocks
#define CHUNK (NBLK / 8)                  // 288 per XCD

// R5 structure (best: 68.3 us) + serpentine band order (L3-retention probe).
// Register-carried row-walking stencil, 4 cols x 8 rows per thread,
// 1-row software prefetch. Collapsed algebra (R0 derivation):
//   Au(i,j) = 0.5 * [ -(v2+v4)@P00 + (v2-v3)@P01 + (v4-v1)@P10 + (v1+v3)@P11 ]
// Weight coords (original 770-wide) never clamp; u clamps rows/right cols at 767.

typedef float f4 __attribute__((ext_vector_type(4)));

__device__ inline f4 ld4u(const float* p) {
    f4 v;
    __builtin_memcpy(&v, p, sizeof(f4));   // 4B-aligned dwordx4
    return v;
}

__global__ __launch_bounds__(256) void diffusion_kernel(
    const float* __restrict__ u,
    const float* __restrict__ a,
    const float* __restrict__ b,
    const float* __restrict__ c,
    const float* __restrict__ alpha_p,
    const float* __restrict__ tau_p,
    float* __restrict__ out)
{
    // XCD-bijective swizzle: 2304 = 8 * 288
    const int bid  = (blockIdx.x & 7) * CHUNK + (blockIdx.x >> 3);
    const int gtid = bid * 256 + threadIdx.x;
    const int tile = gtid % TILES;
    const int braw = (gtid / TILES) % BANDS;
    const int bc   = gtid / (TILES * BANDS);
    // serpentine band order: evens ascending then odds descending (bijective).
    // Sweep ends at band 1, so the next replay's first reads (band 0/1 region)
    // are the most-recently-touched lines in L3.
    const int band = (braw < BANDS / 2) ? (braw * 2) : ((BANDS - 1 - braw) * 2 + 1);
    const int j0 = tile * 4;
    const int i0 = band * ROWS;
    const bool interior = (j0 + 4) < WW;    // false only for tile 191 (j0=764)

    const float alpha = *alpha_p;
    const float tau_h = 0.5f * (*tau_p);
    const float c1 = (1.0f - alpha) * 0.5f;
    const float c2 = alpha * 0.5f;
    const float g  = 1.0f - 2.0f * alpha;

    const float* __restrict__ ub = u + (size_t)bc * (HH * WW);
    const float* __restrict__ ab = a + (size_t)bc * (HP * WP);
    const float* __restrict__ bb = b + (size_t)bc * (HP * WP);
    const float* __restrict__ cb = c + (size_t)bc * (HP * WP);
    float* __restrict__ outb = out + (size_t)bc * (HH * WW);

    // carried: u rows i,i+1,i+2 (6 cols); weight rows i+1,i+2 (5 cols)
    float u0[6], u1[6], u2[6];
    float a1[5], a2[5], b1[5], b2[5], cc1[5], cc2[5];

    auto load_u = [&](int row, float* dst) {
        const float* pr = ub + (size_t)row * WW + j0;
        f4 t0 = *(const f4*)pr;
        f4 t1 = *(const f4*)(pr + (interior ? 4 : 0));
        dst[0] = t0.x; dst[1] = t0.y; dst[2] = t0.z; dst[3] = t0.w;
        dst[4] = interior ? t1.x : t0.w;
        dst[5] = interior ? t1.y : t0.w;
    };
    auto load_w = [&](const float* base, int row, float* dst) {
        const float* pr = base + (size_t)row * WP + (j0 + 1);
        f4 t = ld4u(pr);
        dst[0] = t.x; dst[1] = t.y; dst[2] = t.z; dst[3] = t.w;
        dst[4] = pr[4];
    };

    // prologue: rows for first output row i0
    load_u(i0,     u0);
    load_u(i0 + 1, u1);
    load_u(i0 + 2, u2);
    load_w(ab, i0 + 1, a1);  load_w(ab, i0 + 2, a2);
    load_w(bb, i0 + 1, b1);  load_w(bb, i0 + 2, b2);
    load_w(cb, i0 + 1, cc1); load_w(cb, i0 + 2, cc2);

    auto wts = [&](float Av, float Bv, float Cv,
                   float& w1a, float& w2a, float& w1b, float& w2b,
                   float& w1c, float& w2c) {
        w1a = Av * c1; w2a = Av * c2;
        const float gb = g * fabsf(Bv);
        w1b = (Bv - gb) * 0.25f; w2b = (Bv + gb) * 0.25f;
        w1c = Cv * c1; w2c = Cv * c2;
    };

#pragma unroll
    for (int r = 0; r < ROWS; ++r) {
        const int ri = i0 + r;

        // ---- prefetch row ri+3 (u row-clamped; weight rows <= 769 in bounds) ----
        float pu[6], pa[5], pb[5], pc[5];
        if (r < ROWS - 1) {
            load_u(min(ri + 3, HH - 1), pu);
            load_w(ab, ri + 3, pa);
            load_w(bb, ri + 3, pb);
            load_w(cb, ri + 3, pc);
        }

        // ---- compute output row ri (4 cols) ----
        float res[4];
#pragma unroll
        for (int p = 0; p < 4; ++p) {
            float acc = 0.0f;
            float w1a, w2a, w1b, w2b, w1c, w2c;
            float ux1, ux2, uy1, uy2;

            // P00: s = -(v2+v4)
            wts(a1[p], b1[p], cc1[p], w1a, w2a, w1b, w2b, w1c, w2c);
            ux1 = u0[p+1] - u0[p];   ux2 = u1[p+1] - u1[p];
            uy1 = u1[p]   - u0[p];   uy2 = u1[p+1] - u0[p+1];
            acc -= (w2a + w2b) * ux1 + (w1a + w1b) * ux2
                 + (w2b + w2c) * uy1 + (w1b + w1c) * uy2;

            // P01: s = v2 - v3
            wts(a1[p+1], b1[p+1], cc1[p+1], w1a, w2a, w1b, w2b, w1c, w2c);
            ux1 = u0[p+2] - u0[p+1]; ux2 = u1[p+2] - u1[p+1];
            uy1 = u1[p+1] - u0[p+1]; uy2 = u1[p+2] - u0[p+2];
            acc += (w2a - w1b) * ux1 + (w1a - w2b) * ux2
                 + (w2b - w1c) * uy1 + (w1b - w2c) * uy2;

            // P10: s = v4 - v1
            wts(a2[p], b2[p], cc2[p], w1a, w2a, w1b, w2b, w1c, w2c);
            ux1 = u1[p+1] - u1[p];   ux2 = u2[p+1] - u2[p];
            uy1 = u2[p]   - u1[p];   uy2 = u2[p+1] - u1[p+1];
            acc += (w2b - w1a) * ux1 + (w1b - w2a) * ux2
                 + (w2c - w1b) * uy1 + (w1c - w2b) * uy2;

            // P11: s = v1 + v3
            wts(a2[p+1], b2[p+1], cc2[p+1], w1a, w2a, w1b, w2b, w1c, w2c);
            ux1 = u1[p+2] - u1[p+1]; ux2 = u2[p+2] - u2[p+1];
            uy1 = u2[p+1] - u1[p+1]; uy2 = u2[p+2] - u1[p+2];
            acc += (w1a + w1b) * ux1 + (w2a + w2b) * ux2
                 + (w1b + w1c) * uy1 + (w2b + w2c) * uy2;

            res[p] = u0[p] + tau_h * acc;
        }

        f4 o;
        o.x = res[0]; o.y = res[1]; o.z = res[2]; o.w = res[3];
        __builtin_nontemporal_store(o, (f4*)(outb + (size_t)ri * WW + j0));

        // ---- rotate carried registers (renamed away under full unroll) ----
        if (r < ROWS - 1) {
#pragma unroll
            for (int q = 0; q < 6; ++q) { u0[q] = u1[q]; u1[q] = u2[q]; u2[q] = pu[q]; }
#pragma unroll
            for (int q = 0; q < 5; ++q) {
                a1[q] = a2[q];  a2[q] = pa[q];
                b1[q] = b2[q];  b2[q] = pb[q];
                cc1[q] = cc2[q]; cc2[q] = pc[q];
            }
        }
    }
}

extern "C" void kernel_launch(void* const* d_in, const int* in_sizes, int n_in,
                              void* d_out, int out_size, void* d_ws, size_t ws_size,
                              hipStream_t stream) {
    const float* u     = (const float*)d_in[0];
    const float* a     = (const float*)d_in[1];
    const float* b     = (const float*)d_in[2];
    const float* c     = (const float*)d_in[3];
    const float* alpha = (const float*)d_in[8];
    const float* tau   = (const float*)d_in[9];
    float* out = (float*)d_out;

    dim3 block(256, 1, 1);
    dim3 grid(NBLK, 1, 1);
    diffusion_kernel<<<grid, block, 0, stream>>>(u, a, b, c, alpha, tau, out);
}